// Round 1
// baseline (782.292 us; speedup 1.0000x reference)
//
#include <hip/hip_runtime.h>
#include <stdint.h>

typedef unsigned short u16;
typedef __attribute__((ext_vector_type(8))) __bf16 bf16x8;
typedef __attribute__((ext_vector_type(4))) float f32x4;

__device__ inline u16 f2bf(float f) {
  union { float f; uint32_t u; } v; v.f = f;
  uint32_t u = v.u;
  uint32_t r = (u + 0x7fffu + ((u >> 16) & 1u)) >> 16;  // RNE
  return (u16)r;
}
__device__ inline float bf2f(u16 h) {
  union { uint32_t u; float f; } v; v.u = ((uint32_t)h) << 16;
  return v.f;
}

// ---------------- fp32 -> bf16 cast ----------------
__global__ __launch_bounds__(256) void cast_kernel(const float* __restrict__ in,
                                                   u16* __restrict__ out, int n4) {
  int i = blockIdx.x * 256 + threadIdx.x;
  if (i >= n4) return;
  float4 f = ((const float4*)in)[i];
  ushort4 o;
  o.x = f2bf(f.x); o.y = f2bf(f.y); o.z = f2bf(f.z); o.w = f2bf(f.w);
  ((ushort4*)out)[i] = o;
}

// ---------------- bf16 GEMM, C = A * B^T ----------------
// A: [M,K] bf16 row-major, B: [N,K] bf16 row-major, C: [M,N] (bf16 or f32)
// 128x128 tile, BK=32, 4 waves in 2x2, each wave 64x64 = 4x4 MFMA 16x16x32.
__global__ __launch_bounds__(256) void gemm_bt(const u16* __restrict__ A,
                                               const u16* __restrict__ B,
                                               void* __restrict__ C,
                                               int M, int N, int K, int out_f32)
{
  __shared__ u16 As[128 * 40];  // row stride 40 shorts = 80 B -> 2-way bank alias only
  __shared__ u16 Bs[128 * 40];
  const int tid  = threadIdx.x;
  const int wave = tid >> 6, lane = tid & 63;
  const int col  = lane & 15, quad = lane >> 4;
  const int bm = blockIdx.y, bn = blockIdx.x;
  const int wm = (wave >> 1) * 64, wn = (wave & 1) * 64;
  const size_t arow0 = (size_t)bm * 128, brow0 = (size_t)bn * 128;

  const f32x4 fz = {0.f, 0.f, 0.f, 0.f};
  f32x4 acc[4][4];
  for (int i = 0; i < 4; ++i)
    for (int j = 0; j < 4; ++j) acc[i][j] = fz;

  for (int k0 = 0; k0 < K; k0 += 32) {
    __syncthreads();
    {
      int c = tid;
      #pragma unroll
      for (int it = 0; it < 2; ++it, c += 256) {
        int row = c >> 2, ch = c & 3;   // 128 rows x 4 chunks of 8 bf16
        *(int4*)&As[row * 40 + ch * 8] =
            *(const int4*)(A + (arow0 + row) * K + k0 + ch * 8);
        *(int4*)&Bs[row * 40 + ch * 8] =
            *(const int4*)(B + (brow0 + row) * K + k0 + ch * 8);
      }
    }
    __syncthreads();
    bf16x8 af[4];
    #pragma unroll
    for (int mt = 0; mt < 4; ++mt)
      af[mt] = *(const bf16x8*)&As[(wm + mt * 16 + col) * 40 + quad * 8];
    #pragma unroll
    for (int nt = 0; nt < 4; ++nt) {
      bf16x8 bf = *(const bf16x8*)&Bs[(wn + nt * 16 + col) * 40 + quad * 8];
      #pragma unroll
      for (int mt = 0; mt < 4; ++mt)
        acc[mt][nt] = __builtin_amdgcn_mfma_f32_16x16x32_bf16(af[mt], bf, acc[mt][nt], 0, 0, 0);
    }
  }

  // epilogue: C/D layout col=lane&15, row=quad*4+reg  (m89-verified)
  #pragma unroll
  for (int mt = 0; mt < 4; ++mt)
    #pragma unroll
    for (int nt = 0; nt < 4; ++nt)
      #pragma unroll
      for (int i = 0; i < 4; ++i) {
        size_t grow = arow0 + wm + mt * 16 + quad * 4 + i;
        size_t gcol = brow0 + wn + nt * 16 + col;
        float v = acc[mt][nt][i];
        if (out_f32) ((float*)C)[grow * N + gcol] = v;
        else         ((u16*)C)[grow * N + gcol]   = f2bf(v);
      }
}

// ---------------- RoPE (in-place, bf16, interleaved pairs) ----------------
__global__ __launch_bounds__(256) void rope_kernel(u16* __restrict__ t, int total,
                                                   int H, int S) {
  int idx = blockIdx.x * 256 + threadIdx.x;
  if (idx >= total) return;
  int i = idx & 63;           // freq index
  int r = idx >> 6;
  int h = r % H; r /= H;
  int s = r % S;
  int b = r / S;
  float inv = powf(10000.0f, -(float)(2 * i) / 128.0f);
  float ang = (float)s * inv;
  float sn, cs;
  sincosf(ang, &sn, &cs);
  size_t base = ((size_t)(b * S + s) * H + h) * 128 + 2 * i;
  float t0 = bf2f(t[base]), t1 = bf2f(t[base + 1]);
  t[base]     = f2bf(t0 * cs - t1 * sn);
  t[base + 1] = f2bf(t0 * sn + t1 * cs);
}

// ---------------- causal flash attention, GQA 4:1 ----------------
// grid: (S/64, H, B); 4 waves; wave w owns Q rows q0+w*16 .. +15.
__global__ __launch_bounds__(256) void attn_kernel(const u16* __restrict__ Q,
                                                   const u16* __restrict__ Kg,
                                                   const u16* __restrict__ Vg,
                                                   u16* __restrict__ Ctx,
                                                   int B, int S)
{
  const int qt = blockIdx.x, h = blockIdx.y, b = blockIdx.z;
  const int tid  = threadIdx.x;
  const int wave = tid >> 6, lane = tid & 63;
  const int col  = lane & 15, quad = lane >> 4;
  const int q0   = qt * 64;
  const int kvh  = h >> 2;

  __shared__ u16 Qs[64 * 136];   // 128 + 8 pad
  __shared__ u16 Ks[64 * 136];
  __shared__ u16 Vt[128 * 72];   // V transposed: [d][key], 64 + 8 pad
  __shared__ u16 Ps[4][16 * 72]; // per-wave P tile

  for (int c = tid; c < 1024; c += 256) {
    int row = c >> 4, cc = c & 15;
    *(int4*)&Qs[row * 136 + cc * 8] =
        *(const int4*)(Q + ((size_t)(b * S + q0 + row) * 16 + h) * 128 + cc * 8);
  }
  __syncthreads();

  bf16x8 aq[4];  // Q A-operand frags, stable across kt
  #pragma unroll
  for (int ks = 0; ks < 4; ++ks)
    aq[ks] = *(const bf16x8*)&Qs[(wave * 16 + col) * 136 + ks * 32 + quad * 8];

  const f32x4 fz = {0.f, 0.f, 0.f, 0.f};
  f32x4 o[8];
  #pragma unroll
  for (int nc = 0; nc < 8; ++nc) o[nc] = fz;
  float m_i[4], l_i[4];
  #pragma unroll
  for (int i = 0; i < 4; ++i) { m_i[i] = -1e30f; l_i[i] = 0.f; }

  const float scalef = 0.088388347648318447f;  // 1/sqrt(128)

  for (int kt = 0; kt <= qt; ++kt) {
    __syncthreads();  // previous tile's Vt/Ps reads done
    for (int c = tid; c < 1024; c += 256) {
      int row = c >> 4, cc = c & 15;
      *(int4*)&Ks[row * 136 + cc * 8] =
          *(const int4*)(Kg + ((size_t)(b * S + kt * 64 + row) * 4 + kvh) * 128 + cc * 8);
    }
    for (int c = tid; c < 1024; c += 256) {
      int row = c >> 4, cc = c & 15;
      int4 vv = *(const int4*)(Vg + ((size_t)(b * S + kt * 64 + row) * 4 + kvh) * 128 + cc * 8);
      const u16* pv8 = (const u16*)&vv;
      #pragma unroll
      for (int e = 0; e < 8; ++e) Vt[(cc * 8 + e) * 72 + row] = pv8[e];
    }
    __syncthreads();

    // S = Q K^T  (16x64 per wave)
    f32x4 sc[4];
    #pragma unroll
    for (int nt = 0; nt < 4; ++nt) {
      f32x4 a = fz;
      #pragma unroll
      for (int ks = 0; ks < 4; ++ks) {
        bf16x8 bk = *(const bf16x8*)&Ks[(nt * 16 + col) * 136 + ks * 32 + quad * 8];
        a = __builtin_amdgcn_mfma_f32_16x16x32_bf16(aq[ks], bk, a, 0, 0, 0);
      }
      sc[nt] = a;
    }

    // mask + online softmax. C-layout: lane holds rows quad*4+i, key col nt*16+col.
    float p[4][4];
    float mt_[4] = {-1e30f, -1e30f, -1e30f, -1e30f};
    const int qgbase = q0 + wave * 16 + quad * 4;
    #pragma unroll
    for (int nt = 0; nt < 4; ++nt) {
      int kg = kt * 64 + nt * 16 + col;
      #pragma unroll
      for (int i = 0; i < 4; ++i) {
        float s = sc[nt][i] * scalef;
        if (kg > qgbase + i) s = -1e30f;
        p[nt][i] = s;
        mt_[i] = fmaxf(mt_[i], s);
      }
    }
    #pragma unroll
    for (int i = 0; i < 4; ++i)
      #pragma unroll
      for (int off = 1; off < 16; off <<= 1)
        mt_[i] = fmaxf(mt_[i], __shfl_xor(mt_[i], off));

    float alpha[4], rs[4];
    #pragma unroll
    for (int i = 0; i < 4; ++i) {
      float mn = fmaxf(m_i[i], mt_[i]);
      alpha[i] = __expf(m_i[i] - mn);
      m_i[i] = mn;
      rs[i] = 0.f;
    }
    #pragma unroll
    for (int nt = 0; nt < 4; ++nt)
      #pragma unroll
      for (int i = 0; i < 4; ++i) {
        float e = __expf(p[nt][i] - m_i[i]);
        p[nt][i] = e;
        rs[i] += e;
      }
    #pragma unroll
    for (int i = 0; i < 4; ++i) {
      #pragma unroll
      for (int off = 1; off < 16; off <<= 1)
        rs[i] += __shfl_xor(rs[i], off);
      l_i[i] = l_i[i] * alpha[i] + rs[i];
    }
    #pragma unroll
    for (int nc = 0; nc < 8; ++nc)
      #pragma unroll
      for (int i = 0; i < 4; ++i)
        o[nc][i] *= alpha[i];

    // P: C-layout -> LDS -> A-operand layout (m120 pattern)
    u16* Pw = Ps[wave];
    #pragma unroll
    for (int nt = 0; nt < 4; ++nt)
      #pragma unroll
      for (int i = 0; i < 4; ++i)
        Pw[(quad * 4 + i) * 72 + nt * 16 + col] = f2bf(p[nt][i]);
    __syncthreads();

    bf16x8 ap[2];
    #pragma unroll
    for (int ks = 0; ks < 2; ++ks)
      ap[ks] = *(const bf16x8*)&Pw[col * 72 + ks * 32 + quad * 8];
    #pragma unroll
    for (int nc = 0; nc < 8; ++nc) {
      #pragma unroll
      for (int ks = 0; ks < 2; ++ks) {
        bf16x8 bv = *(const bf16x8*)&Vt[(nc * 16 + col) * 72 + ks * 32 + quad * 8];
        o[nc] = __builtin_amdgcn_mfma_f32_16x16x32_bf16(ap[ks], bv, o[nc], 0, 0, 0);
      }
    }
  }

  #pragma unroll
  for (int nc = 0; nc < 8; ++nc)
    #pragma unroll
    for (int i = 0; i < 4; ++i) {
      int qg = q0 + wave * 16 + quad * 4 + i;
      float val = o[nc][i] / l_i[i];
      Ctx[(size_t)(b * S + qg) * 2048 + h * 128 + nc * 16 + col] = f2bf(val);
    }
}

extern "C" void kernel_launch(void* const* d_in, const int* in_sizes, int n_in,
                              void* d_out, int out_size, void* d_ws, size_t ws_size,
                              hipStream_t stream) {
  const int B = 2, S = 2048, D = 2048, H = 16, KVH = 4;
  const int M = B * S;           // 4096
  const int NKV = KVH * 128;     // 512

  const float* x  = (const float*)d_in[0];
  const float* wq = (const float*)d_in[1];
  const float* wk = (const float*)d_in[2];
  const float* wv = (const float*)d_in[3];
  const float* wo = (const float*)d_in[4];

  char* ws = (char*)d_ws;
  u16* xb  = (u16*)ws; ws += (size_t)M * D * 2;
  u16* wqb = (u16*)ws; ws += (size_t)D * D * 2;
  u16* wkb = (u16*)ws; ws += (size_t)NKV * D * 2;
  u16* wvb = (u16*)ws; ws += (size_t)NKV * D * 2;
  u16* wob = (u16*)ws; ws += (size_t)D * D * 2;
  u16* qb  = (u16*)ws; ws += (size_t)M * D * 2;
  u16* kb  = (u16*)ws; ws += (size_t)M * NKV * 2;
  u16* vb  = (u16*)ws; ws += (size_t)M * NKV * 2;
  u16* ctx = (u16*)ws; ws += (size_t)M * D * 2;

  auto cast = [&](const float* in, u16* out, int n) {
    int n4 = n / 4;
    cast_kernel<<<(n4 + 255) / 256, 256, 0, stream>>>(in, out, n4);
  };
  cast(x,  xb,  M * D);
  cast(wq, wqb, D * D);
  cast(wk, wkb, NKV * D);
  cast(wv, wvb, NKV * D);
  cast(wo, wob, D * D);

  gemm_bt<<<dim3(D / 128,   M / 128), 256, 0, stream>>>(xb, wqb, qb, M, D,   D, 0);
  gemm_bt<<<dim3(NKV / 128, M / 128), 256, 0, stream>>>(xb, wkb, kb, M, NKV, D, 0);
  gemm_bt<<<dim3(NKV / 128, M / 128), 256, 0, stream>>>(xb, wvb, vb, M, NKV, D, 0);

  int tq = M * H * 64;
  rope_kernel<<<(tq + 255) / 256, 256, 0, stream>>>(qb, tq, H, S);
  int tk = M * KVH * 64;
  rope_kernel<<<(tk + 255) / 256, 256, 0, stream>>>(kb, tk, KVH, S);

  attn_kernel<<<dim3(S / 64, H, B), 256, 0, stream>>>(qb, kb, vb, ctx, B, S);

  gemm_bt<<<dim3(D / 128, M / 128), 256, 0, stream>>>(ctx, wob, d_out, M, D, D, 1);
}

// Round 2
// 512.057 us; speedup vs baseline: 1.5277x; 1.5277x over previous
//
#include <hip/hip_runtime.h>
#include <stdint.h>

typedef unsigned short u16;
typedef __attribute__((ext_vector_type(8))) __bf16 bf16x8;
typedef __attribute__((ext_vector_type(4))) float f32x4;

__device__ __forceinline__ u16 f2bf(float f) {
  union { float f; uint32_t u; } v; v.f = f;
  uint32_t u = v.u;
  uint32_t r = (u + 0x7fffu + ((u >> 16) & 1u)) >> 16;  // RNE
  return (u16)r;
}
__device__ __forceinline__ float bf2f(u16 h) {
  union { uint32_t u; float f; } v; v.u = ((uint32_t)h) << 16;
  return v.f;
}

// async 16B/lane global->LDS. LDS dest = wave-uniform base + lane*16 (m104).
__device__ __forceinline__ void gld16(const void* g, void* l) {
  __builtin_amdgcn_global_load_lds(
      (__attribute__((address_space(1))) void*)(uintptr_t)g,
      (__attribute__((address_space(3))) void*)l,
      16, 0, 0);
}

// ---------------- fp32 -> bf16 cast ----------------
__global__ __launch_bounds__(256) void cast_kernel(const float* __restrict__ in,
                                                   u16* __restrict__ out, int n4) {
  int i = blockIdx.x * 256 + threadIdx.x;
  if (i >= n4) return;
  float4 f = ((const float4*)in)[i];
  ushort4 o;
  o.x = f2bf(f.x); o.y = f2bf(f.y); o.z = f2bf(f.z); o.w = f2bf(f.w);
  ((ushort4*)out)[i] = o;
}

// ---------------- bf16 GEMM, C = A * B^T  (m97-style staging) ----------------
// A:[M,K] B:[N,K] bf16 row-major. 128x128 tile, BK=32, 4 waves 2x2, 4x4 MFMA each.
// LDS unpadded [128][32]; 16B chunks xor-swizzled: phys_chunk = log_chunk ^ (row&3).
__global__ __launch_bounds__(256) void gemm_bt(const u16* __restrict__ A,
                                               const u16* __restrict__ B,
                                               void* __restrict__ C,
                                               int M, int N, int K, int out_f32)
{
  __shared__ u16 As[128 * 32];
  __shared__ u16 Bs[128 * 32];
  const int tid  = threadIdx.x;
  const int wave = tid >> 6, lane = tid & 63;
  const int col  = lane & 15, quad = lane >> 4;
  const int bm = blockIdx.y, bn = blockIdx.x;
  const int wm = (wave >> 1) * 64, wn = (wave & 1) * 64;
  const size_t arow0 = (size_t)bm * 128, brow0 = (size_t)bn * 128;

  // staging: wave stages rows wave*32..+31 (2 instrs x 16 rows). lane: row=l>>2, chunk swizzled.
  const int srow = wave * 32 + (lane >> 2);
  const int soff = (((lane & 3) ^ ((lane >> 2) & 3)) * 8);  // shorts
  const u16* Ag = A + (arow0 + srow) * K + soff;
  const u16* Bg = B + (brow0 + srow) * K + soff;
  u16* Asw = As + wave * 32 * 32;
  u16* Bsw = Bs + wave * 32 * 32;
  const int swz = (quad ^ (col & 3)) * 8;  // read-side chunk swizzle (shorts)

  const f32x4 fz = {0.f, 0.f, 0.f, 0.f};
  f32x4 acc[4][4];
  for (int i = 0; i < 4; ++i)
    for (int j = 0; j < 4; ++j) acc[i][j] = fz;

  for (int k0 = 0; k0 < K; k0 += 32) {
    __syncthreads();
    gld16(Ag + k0,                  Asw);
    gld16(Ag + k0 + (size_t)16 * K, Asw + 16 * 32);
    gld16(Bg + k0,                  Bsw);
    gld16(Bg + k0 + (size_t)16 * K, Bsw + 16 * 32);
    __syncthreads();
    bf16x8 af[4];
    #pragma unroll
    for (int mt = 0; mt < 4; ++mt)
      af[mt] = *(const bf16x8*)&As[(wm + mt * 16 + col) * 32 + swz];
    #pragma unroll
    for (int nt = 0; nt < 4; ++nt) {
      bf16x8 bf = *(const bf16x8*)&Bs[(wn + nt * 16 + col) * 32 + swz];
      #pragma unroll
      for (int mt = 0; mt < 4; ++mt)
        acc[mt][nt] = __builtin_amdgcn_mfma_f32_16x16x32_bf16(af[mt], bf, acc[mt][nt], 0, 0, 0);
    }
  }

  // C/D layout: col=lane&15, row=quad*4+reg (m89)
  #pragma unroll
  for (int mt = 0; mt < 4; ++mt)
    #pragma unroll
    for (int nt = 0; nt < 4; ++nt)
      #pragma unroll
      for (int i = 0; i < 4; ++i) {
        size_t grow = arow0 + wm + mt * 16 + quad * 4 + i;
        size_t gcol = brow0 + wn + nt * 16 + col;
        float v = acc[mt][nt][i];
        if (out_f32) ((float*)C)[grow * N + gcol] = v;
        else         ((u16*)C)[grow * N + gcol]   = f2bf(v);
      }
}

// ---------------- RoPE (in-place, bf16, interleaved pairs) ----------------
__global__ __launch_bounds__(256) void rope_kernel(u16* __restrict__ t, int total,
                                                   int H, int S, int rowstride) {
  int idx = blockIdx.x * 256 + threadIdx.x;
  if (idx >= total) return;
  int i = idx & 63;
  int r = idx >> 6;
  int h = r % H; r /= H;
  int s = r % S;
  int b = r / S;
  float inv = powf(10000.0f, -(float)(2 * i) / 128.0f);
  float ang = (float)s * inv;
  float sn, cs;
  sincosf(ang, &sn, &cs);
  size_t base = (size_t)(b * S + s) * rowstride + h * 128 + 2 * i;
  float t0 = bf2f(t[base]), t1 = bf2f(t[base + 1]);
  t[base]     = f2bf(t0 * cs - t1 * sn);
  t[base + 1] = f2bf(t0 * sn + t1 * cs);
}

// ---------------- V transpose: kv[:,512+kvh*128+d] -> Vtg[(b*4+kvh)*128+d][s] ----
__global__ __launch_bounds__(256) void vtrans_kernel(const u16* __restrict__ kv,
                                                     u16* __restrict__ Vtg, int S) {
  __shared__ u16 T[64 * 65];
  const int s0 = blockIdx.x * 64, d0 = blockIdx.y * 64, bk = blockIdx.z;
  const int b = bk >> 2, kvh = bk & 3;
  const u16* src = kv + (size_t)b * S * 1024 + 512 + kvh * 128 + d0;
  #pragma unroll 4
  for (int it = 0; it < 16; ++it) {
    int idx = it * 256 + threadIdx.x;
    int r = idx >> 6, c = idx & 63;           // r: s-offset, c: d-offset
    T[c * 65 + r] = src[(size_t)(s0 + r) * 1024 + c];
  }
  __syncthreads();
  #pragma unroll 4
  for (int it = 0; it < 16; ++it) {
    int idx = it * 256 + threadIdx.x;
    int d = idx >> 6, s = idx & 63;
    Vtg[((size_t)bk * 128 + d0 + d) * S + s0 + s] = T[d * 65 + s];
  }
}

// ---------------- causal flash attention, GQA 4:1 ----------------
// grid (S/128, H, B). 4 waves; wave w owns Q rows q0+w*32..+31 (2 m-tiles of 16).
// K tile 64 keys staged via global_load_lds (xor-swizzled chunks); V staged from
// pre-transposed Vtg. P round-trips per-wave LDS (in-order DS, no barrier).
__global__ __launch_bounds__(256, 3) void attn_kernel(const u16* __restrict__ Q,
                                                      const u16* __restrict__ KV,
                                                      const u16* __restrict__ Vtg,
                                                      u16* __restrict__ Ctx,
                                                      int B, int S)
{
  const int qt = blockIdx.x, h = blockIdx.y, b = blockIdx.z;
  const int tid  = threadIdx.x;
  const int wave = tid >> 6, lane = tid & 63;
  const int col  = lane & 15, quad = lane >> 4;
  const int q0   = qt * 128;
  const int kvh  = h >> 2;

  __shared__ u16 Ks[64 * 128];      // [key][d], chunks swizzled ^ (key&15)
  __shared__ u16 Vt[128 * 64];      // [d][key], chunks swizzled ^ (d&7)
  __shared__ u16 Ps[4][32 * 68];    // per-wave P, pad 68

  // Q fragments straight from global (once per block)
  bf16x8 aq[2][4];
  #pragma unroll
  for (int mt = 0; mt < 2; ++mt)
    #pragma unroll
    for (int ks = 0; ks < 4; ++ks)
      aq[mt][ks] = *(const bf16x8*)(Q + (size_t)(b * S + q0 + wave * 32 + mt * 16 + col) * 2048
                                      + h * 128 + ks * 32 + quad * 8);

  // staging lane constants
  int rK[4], cK[4], rV[4], cV[4];
  #pragma unroll
  for (int i = 0; i < 4; ++i) {
    rK[i] = wave * 16 + i * 4 + (lane >> 4);
    cK[i] = ((lane & 15) ^ (rK[i] & 15)) * 8;
    rV[i] = wave * 32 + i * 8 + (lane >> 3);
    cV[i] = ((lane & 7) ^ (rV[i] & 7)) * 8;
  }
  const u16* KVb = KV + (size_t)b * S * 1024 + kvh * 128;
  const u16* Vtb = Vtg + ((size_t)(b * 4 + kvh) * 128) * S;
  u16* lK[4]; u16* lV[4];
  #pragma unroll
  for (int i = 0; i < 4; ++i) {
    lK[i] = Ks + (wave * 16 + i * 4) * 128;
    lV[i] = Vt + (wave * 32 + i * 8) * 64;
  }
  int swzK[4], swzV[2];
  #pragma unroll
  for (int ks = 0; ks < 4; ++ks) swzK[ks] = ((ks * 4 + quad) ^ col) * 8;
  #pragma unroll
  for (int ks = 0; ks < 2; ++ks) swzV[ks] = ((ks * 4 + quad) ^ (col & 7)) * 8;

  const f32x4 fz = {0.f, 0.f, 0.f, 0.f};
  f32x4 o[2][8];
  #pragma unroll
  for (int mt = 0; mt < 2; ++mt)
    #pragma unroll
    for (int nc = 0; nc < 8; ++nc) o[mt][nc] = fz;
  float m_i[2][4], l_i[2][4];
  #pragma unroll
  for (int mt = 0; mt < 2; ++mt)
    #pragma unroll
    for (int i = 0; i < 4; ++i) { m_i[mt][i] = -1e30f; l_i[mt][i] = 0.f; }

  const float scalef = 0.088388347648318447f;  // 1/sqrt(128)
  const int kt_max = 2 * qt + 1;
  u16* Pw = Ps[wave];

  for (int kt = 0; kt <= kt_max; ++kt) {
    __syncthreads();  // prior tile's Ks/Vt reads done
    #pragma unroll
    for (int i = 0; i < 4; ++i)
      gld16(KVb + (size_t)(kt * 64 + rK[i]) * 1024 + cK[i], lK[i]);
    #pragma unroll
    for (int i = 0; i < 4; ++i)
      gld16(Vtb + (size_t)rV[i] * S + kt * 64 + cV[i], lV[i]);
    __syncthreads();  // drains vmcnt -> staging visible

    if (q0 + wave * 32 + 31 >= kt * 64) {  // wave-uniform: skip fully-masked tiles
      #pragma unroll
      for (int mt = 0; mt < 2; ++mt) {
        // S = Q K^T (16x64)
        f32x4 sc[4];
        #pragma unroll
        for (int nt = 0; nt < 4; ++nt) {
          f32x4 a = fz;
          #pragma unroll
          for (int ks = 0; ks < 4; ++ks) {
            bf16x8 bk = *(const bf16x8*)&Ks[(nt * 16 + col) * 128 + swzK[ks]];
            a = __builtin_amdgcn_mfma_f32_16x16x32_bf16(aq[mt][ks], bk, a, 0, 0, 0);
          }
          sc[nt] = a;
        }

        // mask + online softmax; lane holds rows quad*4+i, key col nt*16+col
        float p[4][4];
        float mx[4] = {-1e30f, -1e30f, -1e30f, -1e30f};
        const int qgb = q0 + wave * 32 + mt * 16 + quad * 4;
        #pragma unroll
        for (int nt = 0; nt < 4; ++nt) {
          int kg = kt * 64 + nt * 16 + col;
          #pragma unroll
          for (int i = 0; i < 4; ++i) {
            float s = sc[nt][i] * scalef;
            if (kg > qgb + i) s = -1e30f;
            p[nt][i] = s;
            mx[i] = fmaxf(mx[i], s);
          }
        }
        #pragma unroll
        for (int i = 0; i < 4; ++i)
          #pragma unroll
          for (int off = 1; off < 16; off <<= 1)
            mx[i] = fmaxf(mx[i], __shfl_xor(mx[i], off));

        float alpha[4], rs[4];
        #pragma unroll
        for (int i = 0; i < 4; ++i) {
          float mn = fmaxf(m_i[mt][i], mx[i]);
          alpha[i] = __expf(m_i[mt][i] - mn);
          m_i[mt][i] = mn;
          rs[i] = 0.f;
        }
        #pragma unroll
        for (int nt = 0; nt < 4; ++nt)
          #pragma unroll
          for (int i = 0; i < 4; ++i) {
            float e = __expf(p[nt][i] - m_i[mt][i]);
            p[nt][i] = e;
            rs[i] += e;
          }
        #pragma unroll
        for (int i = 0; i < 4; ++i) {
          #pragma unroll
          for (int off = 1; off < 16; off <<= 1)
            rs[i] += __shfl_xor(rs[i], off);
          l_i[mt][i] = l_i[mt][i] * alpha[i] + rs[i];
        }
        #pragma unroll
        for (int nc = 0; nc < 8; ++nc)
          #pragma unroll
          for (int i = 0; i < 4; ++i)
            o[mt][nc][i] *= alpha[i];

        // P: C-layout -> per-wave LDS -> A-layout (same-wave DS is in-order)
        #pragma unroll
        for (int nt = 0; nt < 4; ++nt)
          #pragma unroll
          for (int i = 0; i < 4; ++i)
            Pw[(mt * 16 + quad * 4 + i) * 68 + nt * 16 + col] = f2bf(p[nt][i]);
        __asm__ volatile("" ::: "memory");
        bf16x8 ap[2];
        #pragma unroll
        for (int ks = 0; ks < 2; ++ks)
          ap[ks] = *(const bf16x8*)&Pw[(mt * 16 + col) * 68 + ks * 32 + quad * 8];
        #pragma unroll
        for (int nc = 0; nc < 8; ++nc) {
          #pragma unroll
          for (int ks = 0; ks < 2; ++ks) {
            bf16x8 bv = *(const bf16x8*)&Vt[(nc * 16 + col) * 64 + swzV[ks]];
            o[mt][nc] = __builtin_amdgcn_mfma_f32_16x16x32_bf16(ap[ks], bv, o[mt][nc], 0, 0, 0);
          }
        }
      }
    }
  }

  #pragma unroll
  for (int mt = 0; mt < 2; ++mt)
    #pragma unroll
    for (int nc = 0; nc < 8; ++nc)
      #pragma unroll
      for (int i = 0; i < 4; ++i) {
        int qg = q0 + wave * 32 + mt * 16 + quad * 4 + i;
        float val = o[mt][nc][i] / l_i[mt][i];
        Ctx[(size_t)(b * S + qg) * 2048 + h * 128 + nc * 16 + col] = f2bf(val);
      }
}

extern "C" void kernel_launch(void* const* d_in, const int* in_sizes, int n_in,
                              void* d_out, int out_size, void* d_ws, size_t ws_size,
                              hipStream_t stream) {
  const int B = 2, S = 2048, D = 2048, H = 16, KVH = 4;
  const int M = B * S;            // 4096
  const int NKV2 = 2 * KVH * 128; // 1024 (K cols 0..511, V cols 512..1023)

  const float* x  = (const float*)d_in[0];
  const float* wq = (const float*)d_in[1];
  const float* wk = (const float*)d_in[2];
  const float* wv = (const float*)d_in[3];
  const float* wo = (const float*)d_in[4];

  char* ws = (char*)d_ws;
  u16* xb   = (u16*)ws; ws += (size_t)M * D * 2;
  u16* wqb  = (u16*)ws; ws += (size_t)D * D * 2;
  u16* wkvb = (u16*)ws; ws += (size_t)NKV2 * D * 2;
  u16* wob  = (u16*)ws; ws += (size_t)D * D * 2;
  u16* qb   = (u16*)ws; ws += (size_t)M * D * 2;
  u16* kvb  = (u16*)ws; ws += (size_t)M * NKV2 * 2;
  u16* vtg  = (u16*)ws; ws += (size_t)B * KVH * 128 * S * 2;
  u16* ctx  = (u16*)ws; ws += (size_t)M * D * 2;

  auto cast = [&](const float* in, u16* out, size_t n) {
    int n4 = (int)(n / 4);
    cast_kernel<<<(n4 + 255) / 256, 256, 0, stream>>>(in, out, n4);
  };
  cast(x,  xb,  (size_t)M * D);
  cast(wq, wqb, (size_t)D * D);
  cast(wk, wkvb,               (size_t)512 * D);
  cast(wv, wkvb + (size_t)512 * D, (size_t)512 * D);
  cast(wo, wob, (size_t)D * D);

  gemm_bt<<<dim3(D / 128,    M / 128), 256, 0, stream>>>(xb, wqb,  qb,  M, D,    D, 0);
  gemm_bt<<<dim3(NKV2 / 128, M / 128), 256, 0, stream>>>(xb, wkvb, kvb, M, NKV2, D, 0);

  int tq = M * H * 64;
  rope_kernel<<<(tq + 255) / 256, 256, 0, stream>>>(qb, tq, H, S, 2048);
  int tk = M * KVH * 64;
  rope_kernel<<<(tk + 255) / 256, 256, 0, stream>>>(kvb, tk, KVH, S, 1024);

  vtrans_kernel<<<dim3(S / 64, 2, B * KVH), 256, 0, stream>>>(kvb, vtg, S);

  attn_kernel<<<dim3(S / 128, H, B), 256, 0, stream>>>(qb, kvb, vtg, ctx, B, S);

  gemm_bt<<<dim3(D / 128, M / 128), 256, 0, stream>>>(ctx, wob, d_out, M, D, D, 1);
}

// Round 3
// 394.384 us; speedup vs baseline: 1.9836x; 1.2984x over previous
//
#include <hip/hip_runtime.h>
#include <stdint.h>

typedef unsigned short u16;
typedef __attribute__((ext_vector_type(8))) __bf16 bf16x8;
typedef __attribute__((ext_vector_type(4))) float f32x4;

__device__ __forceinline__ u16 f2bf(float f) {
  union { float f; uint32_t u; } v; v.f = f;
  uint32_t u = v.u;
  uint32_t r = (u + 0x7fffu + ((u >> 16) & 1u)) >> 16;  // RNE
  return (u16)r;
}
__device__ __forceinline__ float bf2f(u16 h) {
  union { uint32_t u; float f; } v; v.u = ((uint32_t)h) << 16;
  return v.f;
}

// async 16B/lane global->LDS. LDS dest = wave-uniform base + lane*16 (m104).
__device__ __forceinline__ void gld16(const void* g, void* l) {
  __builtin_amdgcn_global_load_lds(
      (__attribute__((address_space(1))) void*)(uintptr_t)g,
      (__attribute__((address_space(3))) void*)l,
      16, 0, 0);
}

// ---------------- fused fp32 -> bf16 cast of all 5 inputs ----------------
// float4-granular regions (compile-time): x | wq | wk | wv | wo
__global__ __launch_bounds__(256) void cast_all(const float* __restrict__ x,
                                                const float* __restrict__ wq,
                                                const float* __restrict__ wk,
                                                const float* __restrict__ wv,
                                                const float* __restrict__ wo,
                                                u16* __restrict__ xb,
                                                u16* __restrict__ wqkv,
                                                u16* __restrict__ wob) {
  int i = blockIdx.x * 256 + threadIdx.x;
  const float* src; u16* dst; int off;
  if (i < 2097152)      { src = x;  dst = xb;   off = i; }
  else if (i < 3145728) { src = wq; dst = wqkv; off = i - 3145728 + 1048576; }
  else if (i < 3407872) { src = wk; dst = wqkv; off = i - 3407872 + 262144 + 1048576; }
  else if (i < 3670016) { src = wv; dst = wqkv; off = i - 3670016 + 262144 + 1310720; }
  else                  { src = wo; dst = wob;  off = i - 3670016; }
  // recover region-local float4 index
  int loc;
  if (i < 2097152)      loc = i;
  else if (i < 3145728) loc = i - 2097152;
  else if (i < 3407872) loc = i - 3145728;
  else if (i < 3670016) loc = i - 3407872;
  else                  loc = i - 3670016;
  // region base in float4 units within dst
  int base;
  if (i < 2097152)      base = 0;
  else if (i < 3145728) base = 0;          // wq rows 0..2047 of wqkv
  else if (i < 3407872) base = 1048576;    // wk rows 2048..2559
  else if (i < 3670016) base = 1310720;    // wv rows 2560..3071
  else                  base = 0;
  off = base + loc;
  float4 f = ((const float4*)src)[loc];
  ushort4 o;
  o.x = f2bf(f.x); o.y = f2bf(f.y); o.z = f2bf(f.z); o.w = f2bf(f.w);
  ((ushort4*)dst)[off] = o;
}

// ---------------- bf16 GEMM, C = A * B^T  (m97-style staging) ----------------
__global__ __launch_bounds__(256) void gemm_bt(const u16* __restrict__ A,
                                               const u16* __restrict__ B,
                                               void* __restrict__ C,
                                               int M, int N, int K, int out_f32)
{
  __shared__ u16 As[128 * 32];
  __shared__ u16 Bs[128 * 32];
  const int tid  = threadIdx.x;
  const int wave = tid >> 6, lane = tid & 63;
  const int col  = lane & 15, quad = lane >> 4;
  const int bm = blockIdx.y, bn = blockIdx.x;
  const int wm = (wave >> 1) * 64, wn = (wave & 1) * 64;
  const size_t arow0 = (size_t)bm * 128, brow0 = (size_t)bn * 128;

  const int srow = wave * 32 + (lane >> 2);
  const int soff = (((lane & 3) ^ ((lane >> 2) & 3)) * 8);
  const u16* Ag = A + (arow0 + srow) * K + soff;
  const u16* Bg = B + (brow0 + srow) * K + soff;
  u16* Asw = As + wave * 32 * 32;
  u16* Bsw = Bs + wave * 32 * 32;
  const int swz = (quad ^ (col & 3)) * 8;

  const f32x4 fz = {0.f, 0.f, 0.f, 0.f};
  f32x4 acc[4][4];
  for (int i = 0; i < 4; ++i)
    for (int j = 0; j < 4; ++j) acc[i][j] = fz;

  for (int k0 = 0; k0 < K; k0 += 32) {
    __syncthreads();
    gld16(Ag + k0,                  Asw);
    gld16(Ag + k0 + (size_t)16 * K, Asw + 16 * 32);
    gld16(Bg + k0,                  Bsw);
    gld16(Bg + k0 + (size_t)16 * K, Bsw + 16 * 32);
    __syncthreads();
    bf16x8 af[4];
    #pragma unroll
    for (int mt = 0; mt < 4; ++mt)
      af[mt] = *(const bf16x8*)&As[(wm + mt * 16 + col) * 32 + swz];
    #pragma unroll
    for (int nt = 0; nt < 4; ++nt) {
      bf16x8 bf = *(const bf16x8*)&Bs[(wn + nt * 16 + col) * 32 + swz];
      #pragma unroll
      for (int mt = 0; mt < 4; ++mt)
        acc[mt][nt] = __builtin_amdgcn_mfma_f32_16x16x32_bf16(af[mt], bf, acc[mt][nt], 0, 0, 0);
    }
  }

  #pragma unroll
  for (int mt = 0; mt < 4; ++mt)
    #pragma unroll
    for (int nt = 0; nt < 4; ++nt)
      #pragma unroll
      for (int i = 0; i < 4; ++i) {
        size_t grow = arow0 + wm + mt * 16 + quad * 4 + i;
        size_t gcol = brow0 + wn + nt * 16 + col;
        float v = acc[mt][nt][i];
        if (out_f32) ((float*)C)[grow * N + gcol] = v;
        else         ((u16*)C)[grow * N + gcol]   = f2bf(v);
      }
}

// ---------------- RoPE over fused qkv buffer (row stride 3072) ----------------
// heads hh: 0..15 = Q (cols hh*128, post-scale by qscale), 16..19 = K (cols 2048+(hh-16)*128)
__global__ __launch_bounds__(256) void rope_kernel(u16* __restrict__ t, int S, float qscale) {
  int idx = blockIdx.x * 256 + threadIdx.x;   // total = B*S*20*64
  int i = idx & 63;
  int r = idx >> 6;
  int hh = r % 20; r /= 20;
  int s = r % S;
  int b = r / S;
  float inv = powf(10000.0f, -(float)(2 * i) / 128.0f);
  float ang = (float)s * inv;
  float sn, cs;
  sincosf(ang, &sn, &cs);
  int colb = (hh < 16) ? hh * 128 : 2048 + (hh - 16) * 128;
  float osc = (hh < 16) ? qscale : 1.0f;
  size_t base = (size_t)(b * S + s) * 3072 + colb + 2 * i;
  float t0 = bf2f(t[base]), t1 = bf2f(t[base + 1]);
  t[base]     = f2bf((t0 * cs - t1 * sn) * osc);
  t[base + 1] = f2bf((t0 * sn + t1 * cs) * osc);
}

// ---------------- V transpose: qkv[:,2560+kvh*128+d] -> Vtg[(b*4+kvh)*128+d][s] ----
__global__ __launch_bounds__(256) void vtrans_kernel(const u16* __restrict__ qkv,
                                                     u16* __restrict__ Vtg, int S) {
  __shared__ u16 T[64 * 65];
  const int s0 = blockIdx.x * 64, d0 = blockIdx.y * 64, bk = blockIdx.z;
  const int b = bk >> 2, kvh = bk & 3;
  const u16* src = qkv + (size_t)b * S * 3072 + 2560 + kvh * 128 + d0;
  #pragma unroll 4
  for (int it = 0; it < 16; ++it) {
    int idx = it * 256 + threadIdx.x;
    int r = idx >> 6, c = idx & 63;
    T[c * 65 + r] = src[(size_t)(s0 + r) * 3072 + c];
  }
  __syncthreads();
  #pragma unroll 4
  for (int it = 0; it < 16; ++it) {
    int idx = it * 256 + threadIdx.x;
    int d = idx >> 6, s = idx & 63;
    Vtg[((size_t)bk * 128 + d0 + d) * S + s0 + s] = T[d * 65 + s];
  }
}

// ---------------- causal flash attention, GQA 4:1, no-max softmax ----------------
// 1-D grid 512. slot0 (first 256): qt=15-j (heavy), slot1: qt=j. Pairs sum to 34 tiles.
__global__ __launch_bounds__(256, 3) void attn_kernel(const u16* __restrict__ QKV,
                                                      const u16* __restrict__ Vtg,
                                                      u16* __restrict__ Ctx,
                                                      int B, int S)
{
  const int g = blockIdx.x;
  const int slot = g >> 8, pp = g & 255;
  const int j = pp & 7, hb = pp >> 3;
  const int h = hb & 15, b = hb >> 4;
  const int qt = slot ? j : 15 - j;

  const int tid  = threadIdx.x;
  const int wave = tid >> 6, lane = tid & 63;
  const int col  = lane & 15, quad = lane >> 4;
  const int q0   = qt * 128;
  const int kvh  = h >> 2;

  __shared__ u16 Ks[64 * 128];
  __shared__ u16 Vt[128 * 64];
  __shared__ u16 Ps[4][32 * 68];

  // Q fragments (already scaled by log2e/sqrt(128) in rope)
  bf16x8 aq[2][4];
  #pragma unroll
  for (int mt = 0; mt < 2; ++mt)
    #pragma unroll
    for (int ks = 0; ks < 4; ++ks)
      aq[mt][ks] = *(const bf16x8*)(QKV + (size_t)(b * S + q0 + wave * 32 + mt * 16 + col) * 3072
                                        + h * 128 + ks * 32 + quad * 8);

  int rK[4], cK[4], rV[4], cV[4];
  #pragma unroll
  for (int i = 0; i < 4; ++i) {
    rK[i] = wave * 16 + i * 4 + (lane >> 4);
    cK[i] = ((lane & 15) ^ (rK[i] & 15)) * 8;
    rV[i] = wave * 32 + i * 8 + (lane >> 3);
    cV[i] = ((lane & 7) ^ (rV[i] & 7)) * 8;
  }
  const u16* KVb = QKV + (size_t)b * S * 3072 + 2048 + kvh * 128;
  const u16* Vtb = Vtg + ((size_t)(b * 4 + kvh) * 128) * S;
  u16* lK[4]; u16* lV[4];
  #pragma unroll
  for (int i = 0; i < 4; ++i) {
    lK[i] = Ks + (wave * 16 + i * 4) * 128;
    lV[i] = Vt + (wave * 32 + i * 8) * 64;
  }
  int swzK[4], swzV[2];
  #pragma unroll
  for (int ks = 0; ks < 4; ++ks) swzK[ks] = ((ks * 4 + quad) ^ col) * 8;
  #pragma unroll
  for (int ks = 0; ks < 2; ++ks) swzV[ks] = ((ks * 4 + quad) ^ (col & 7)) * 8;

  const f32x4 fz = {0.f, 0.f, 0.f, 0.f};
  f32x4 o[2][8];
  #pragma unroll
  for (int mt = 0; mt < 2; ++mt)
    #pragma unroll
    for (int nc = 0; nc < 8; ++nc) o[mt][nc] = fz;
  float rs[2][4];
  #pragma unroll
  for (int mt = 0; mt < 2; ++mt)
    #pragma unroll
    for (int i = 0; i < 4; ++i) rs[mt][i] = 0.f;

  const int kt_max = 2 * qt + 1;
  u16* Pw = Ps[wave];

  for (int kt = 0; kt <= kt_max; ++kt) {
    __syncthreads();
    #pragma unroll
    for (int i = 0; i < 4; ++i)
      gld16(KVb + (size_t)(kt * 64 + rK[i]) * 3072 + cK[i], lK[i]);
    #pragma unroll
    for (int i = 0; i < 4; ++i)
      gld16(Vtb + (size_t)rV[i] * S + kt * 64 + cV[i], lV[i]);
    __syncthreads();

    #pragma unroll
    for (int mt = 0; mt < 2; ++mt) {
      const int row0 = q0 + wave * 32 + mt * 16;
      if (kt * 64 > row0 + 15) continue;          // fully masked mtile (wave-uniform)
      // S = Q K^T (16x64), exponent-ready (scale folded into Q)
      f32x4 sc[4];
      #pragma unroll
      for (int nt = 0; nt < 4; ++nt) {
        f32x4 a = fz;
        #pragma unroll
        for (int ks = 0; ks < 4; ++ks) {
          bf16x8 bk = *(const bf16x8*)&Ks[(nt * 16 + col) * 128 + swzK[ks]];
          a = __builtin_amdgcn_mfma_f32_16x16x32_bf16(aq[mt][ks], bk, a, 0, 0, 0);
        }
        sc[nt] = a;
      }

      const bool need_mask = (kt * 64 + 63 > row0);  // diagonal tile (wave-uniform)
      float p[4][4];
      #pragma unroll
      for (int nt = 0; nt < 4; ++nt) {
        int kg = kt * 64 + nt * 16 + col;
        #pragma unroll
        for (int i = 0; i < 4; ++i) {
          float s = sc[nt][i];
          if (need_mask && kg > row0 + quad * 4 + i) s = -__builtin_inff();
          float e = exp2f(s);
          p[nt][i] = e;
          rs[mt][i] += e;
        }
      }

      // P: C-layout -> per-wave LDS -> A-layout (truncate-to-bf16; same-wave DS in-order)
      #pragma unroll
      for (int nt = 0; nt < 4; ++nt)
        #pragma unroll
        for (int i = 0; i < 4; ++i)
          Pw[(mt * 16 + quad * 4 + i) * 68 + nt * 16 + col] =
              (u16)(__float_as_uint(p[nt][i]) >> 16);
      __asm__ volatile("" ::: "memory");
      bf16x8 ap[2];
      #pragma unroll
      for (int ks = 0; ks < 2; ++ks)
        ap[ks] = *(const bf16x8*)&Pw[(mt * 16 + col) * 68 + ks * 32 + quad * 8];
      #pragma unroll
      for (int nc = 0; nc < 8; ++nc) {
        #pragma unroll
        for (int ks = 0; ks < 2; ++ks) {
          bf16x8 bv = *(const bf16x8*)&Vt[(nc * 16 + col) * 64 + swzV[ks]];
          o[mt][nc] = __builtin_amdgcn_mfma_f32_16x16x32_bf16(ap[ks], bv, o[mt][nc], 0, 0, 0);
        }
      }
    }
  }

  // deferred row-sum: reduce rs across the 16 col-lanes, then normalize
  #pragma unroll
  for (int mt = 0; mt < 2; ++mt) {
    float linv[4];
    #pragma unroll
    for (int i = 0; i < 4; ++i) {
      float v = rs[mt][i];
      #pragma unroll
      for (int off = 1; off < 16; off <<= 1)
        v += __shfl_xor(v, off);
      linv[i] = 1.0f / v;
    }
    #pragma unroll
    for (int nc = 0; nc < 8; ++nc)
      #pragma unroll
      for (int i = 0; i < 4; ++i) {
        int qg = q0 + wave * 32 + mt * 16 + quad * 4 + i;
        Ctx[(size_t)(b * S + qg) * 2048 + h * 128 + nc * 16 + col] =
            f2bf(o[mt][nc][i] * linv[i]);
      }
  }
}

extern "C" void kernel_launch(void* const* d_in, const int* in_sizes, int n_in,
                              void* d_out, int out_size, void* d_ws, size_t ws_size,
                              hipStream_t stream) {
  const int B = 2, S = 2048, D = 2048;
  const int M = B * S;            // 4096
  const int NQKV = 3072;          // q 0..2047 | k 2048..2559 | v 2560..3071

  const float* x  = (const float*)d_in[0];
  const float* wq = (const float*)d_in[1];
  const float* wk = (const float*)d_in[2];
  const float* wv = (const float*)d_in[3];
  const float* wo = (const float*)d_in[4];

  char* ws = (char*)d_ws;
  u16* xb    = (u16*)ws; ws += (size_t)M * D * 2;
  u16* wqkvb = (u16*)ws; ws += (size_t)NQKV * D * 2;
  u16* wob   = (u16*)ws; ws += (size_t)D * D * 2;
  u16* qkvb  = (u16*)ws; ws += (size_t)M * NQKV * 2;
  u16* vtg   = (u16*)ws; ws += (size_t)B * 4 * 128 * S * 2;
  u16* ctx   = (u16*)ws; ws += (size_t)M * D * 2;

  cast_all<<<18432, 256, 0, stream>>>(x, wq, wk, wv, wo, xb, wqkvb, wob);

  gemm_bt<<<dim3(NQKV / 128, M / 128), 256, 0, stream>>>(xb, wqkvb, qkvb, M, NQKV, D, 0);

  // qscale = log2(e)/sqrt(128), folded so attention uses exp2 directly
  const float qscale = 0.12751744515623627f;
  rope_kernel<<<(M * 20 * 64) / 256, 256, 0, stream>>>(qkvb, S, qscale);

  vtrans_kernel<<<dim3(S / 64, 2, B * 4), 256, 0, stream>>>(qkvb, vtg, S);

  attn_kernel<<<512, 256, 0, stream>>>(qkvb, vtg, ctx, B, S);

  gemm_bt<<<dim3(D / 128, M / 128), 256, 0, stream>>>(ctx, wob, d_out, M, D, D, 1);
}